// Round 7
// baseline (598.202 us; speedup 1.0000x reference)
//
#include <hip/hip_runtime.h>

#define C_LAB 24
#define EDIM 16
#define PPIX (768 * 768)
#define NB 4
#define VT_PX 512

// ws layout in 4-byte words:
// [0,96)        counts (int)
// [96,1632)     sums (float)    N*C*E
// [1632,3168)   means (float)   N*C*E
// [3168,3172)   reg per n
// [3172,3176)   triplet per n
// [3176,3180)   varsum per n
// [3180]        probe sink (calibration only, not used in output)
#define WS_WORDS 3184

__global__ __launch_bounds__(256) void k_zero(int* ws) {
    for (int i = threadIdx.x; i < WS_WORDS; i += 256) ws[i] = 0;
}

// Calibration: pure contiguous streaming read of the full input tensor.
// Measures achievable BW in this harness/graph, independent of kernel logic.
__global__ __launch_bounds__(256) void k_probe(const float* __restrict__ in,
                                               float* __restrict__ probev) {
    const size_t total4 = (size_t)NB * EDIM * PPIX / 4;
    const float4* p4 = reinterpret_cast<const float4*>(in);
    float s = 0.f;
    for (size_t i = (size_t)blockIdx.x * 256 + threadIdx.x; i < total4;
         i += (size_t)gridDim.x * 256) {
        float4 v = p4[i];
        s += v.x + v.y + v.z + v.w;
    }
    for (int o = 32; o; o >>= 1) s += __shfl_down(s, o, 64);
    if ((threadIdx.x & 63) == 0) atomicAdd(probev, s);
}

// Channel-separated accumulation: cluster sums are separable per channel
// (sums[c][e] = sum over pixels with label c of x[e]). Each block handles ONE
// (n, e) and a contiguous 4096-pixel run -> every wave streams contiguous
// addresses. This removes the 16-stream 2.25MiB (0x240000) stride pattern
// that kept all prior rounds at ~210us (stride preserves bits<18: same L2
// set / HBM channel / DRAM bank for all 16 streams of a wave).
__global__ __launch_bounds__(256, 4) void k_accum_e(const float* __restrict__ in,
                                                    const int* __restrict__ tgt,
                                                    float* __restrict__ sums,
                                                    int* __restrict__ counts) {
    const int n = blockIdx.y, e = blockIdx.z, tid = threadIdx.x;
    __shared__ float ls[4][28];   // 4 quarter-wave replicas, 24 bins padded
    __shared__ int lc[4][28];
    if (tid < 112) { (&ls[0][0])[tid] = 0.f; (&lc[0][0])[tid] = 0; }
    __syncthreads();

    const int rep = (tid >> 4) & 3;
    const size_t pix0 = (size_t)blockIdx.x * 4096;
    const float* bp = in + (size_t)(n * EDIM + e) * PPIX + pix0;
    const int* lp = tgt + (size_t)n * PPIX + pix0;

    float4 x[4];
    int4 lb[4];
#pragma unroll
    for (int k = 0; k < 4; ++k) {
        x[k] = reinterpret_cast<const float4*>(bp)[k * 256 + tid];
        lb[k] = reinterpret_cast<const int4*>(lp)[k * 256 + tid];
    }
#pragma unroll
    for (int k = 0; k < 4; ++k) {
        atomicAdd(&ls[rep][lb[k].x], x[k].x);
        atomicAdd(&ls[rep][lb[k].y], x[k].y);
        atomicAdd(&ls[rep][lb[k].z], x[k].z);
        atomicAdd(&ls[rep][lb[k].w], x[k].w);
        if (e == 0) {
            atomicAdd(&lc[rep][lb[k].x], 1);
            atomicAdd(&lc[rep][lb[k].y], 1);
            atomicAdd(&lc[rep][lb[k].z], 1);
            atomicAdd(&lc[rep][lb[k].w], 1);
        }
    }
    __syncthreads();

    if (tid < C_LAB) {
        const float s = ls[0][tid] + ls[1][tid] + ls[2][tid] + ls[3][tid];
        atomicAdd(&sums[((size_t)n * C_LAB + tid) * EDIM + e], s);
        if (e == 0)
            atomicAdd(&counts[n * C_LAB + tid],
                      lc[0][tid] + lc[1][tid] + lc[2][tid] + lc[3][tid]);
    }
}

__global__ __launch_bounds__(128) void k_means(const float* __restrict__ sums,
                                               const int* __restrict__ counts,
                                               float* __restrict__ means,
                                               float* __restrict__ regv) {
    const int t = threadIdx.x;
    if (t >= NB * C_LAB) return;
    const int n = t / C_LAB;
    const float inv = 1.f / (float)counts[t];
    float s2 = 0.f;
#pragma unroll
    for (int e = 0; e < EDIM; ++e) {
        float m = sums[t * EDIM + e] * inv;
        means[t * EDIM + e] = m;
        s2 += m * m;
    }
    float d = sqrtf(s2) - 1.f;
    atomicAdd(&regv[n], d * d);
}

__global__ __launch_bounds__(256) void k_triplet(const float* __restrict__ means,
                                                 const int* __restrict__ eattr,
                                                 const int* __restrict__ erep,
                                                 float* __restrict__ tripv) {
    const int n = blockIdx.x;
    const int tid = threadIdx.x;
    __shared__ float cm[C_LAB][EDIM];
    __shared__ float dA[200], dR[200];
    __shared__ int a0[200], a1[200], r0[200], r1[200];
    for (int i = tid; i < C_LAB * EDIM; i += 256)
        (&cm[0][0])[i] = means[n * C_LAB * EDIM + i];
    __syncthreads();
    if (tid < 200) {
        int i0 = eattr[n * 400 + tid], i1 = eattr[n * 400 + 200 + tid];
        a0[tid] = i0; a1[tid] = i1;
        float s = 0.f;
#pragma unroll
        for (int e = 0; e < EDIM; ++e) {
            float d = cm[i0][e] - cm[i1][e] + 1e-6f;
            s += d * d;
        }
        dA[tid] = s;
        i0 = erep[n * 400 + tid]; i1 = erep[n * 400 + 200 + tid];
        r0[tid] = i0; r1[tid] = i1;
        s = 0.f;
#pragma unroll
        for (int e = 0; e < EDIM; ++e) {
            float d = cm[i0][e] - cm[i1][e] + 1e-6f;
            s += d * d;
        }
        dR[tid] = s;
    }
    __syncthreads();

    float sum = 0.f;
    int cnt = 0;
    for (int idx = tid; idx < 200 * 200; idx += 256) {
        const int a = idx / 200;
        const int r = idx - a * 200;
        const int m = (a0[a] == r0[r]) + (a0[a] == r1[r]) +
                      (a1[a] == r0[r]) + (a1[a] == r1[r]);
        const float t = 0.5f * (dA[a] - dR[r]) + 0.01f;
        if (m == 1 && t > 0.f) { sum += t; cnt++; }
    }
    for (int o = 32; o; o >>= 1) {
        sum += __shfl_down(sum, o, 64);
        cnt += __shfl_down(cnt, o, 64);
    }
    __shared__ float rs[4];
    __shared__ int rc[4];
    if ((tid & 63) == 0) { rs[tid >> 6] = sum; rc[tid >> 6] = cnt; }
    __syncthreads();
    if (tid == 0) {
        float S = rs[0] + rs[1] + rs[2] + rs[3];
        int Cn = rc[0] + rc[1] + rc[2] + rc[3];
        tripv[n] = (Cn > 0) ? S / (float)Cn : 0.f;
    }
}

// Variance via LDS transpose: load phase streams contiguous per-channel
// float4 runs (wave w owns channels 4w..4w+3) into a 16x512 LDS tile; compute
// phase reads pixel-major from LDS (lane-consecutive -> conflict-free).
__global__ __launch_bounds__(256, 4) void k_var_t(const float* __restrict__ in,
                                                  const int* __restrict__ tgt,
                                                  const float* __restrict__ means,
                                                  const int* __restrict__ counts,
                                                  float* __restrict__ varv) {
    const int n = blockIdx.y, tid = threadIdx.x;
    const int w = tid >> 6, lane = tid & 63;
    __shared__ float xt[EDIM][VT_PX + 4];   // row stride 516 words, 16B-aligned
    __shared__ float lm[C_LAB][EDIM + 1];
    __shared__ float licnt[C_LAB];
    for (int i = tid; i < C_LAB * EDIM; i += 256)
        lm[i >> 4][i & 15] = means[(size_t)n * C_LAB * EDIM + i];
    if (tid < C_LAB) licnt[tid] = 1.f / (float)counts[n * C_LAB + tid];

    const size_t pix0 = (size_t)blockIdx.x * VT_PX;
#pragma unroll
    for (int ee = 0; ee < 4; ++ee) {
        const int e = w * 4 + ee;
        const float4* src =
            reinterpret_cast<const float4*>(in + (size_t)(n * EDIM + e) * PPIX + pix0);
#pragma unroll
        for (int k = 0; k < 2; ++k) {
            const int p4 = k * 64 + lane;
            const float4 v = src[p4];
            *reinterpret_cast<float4*>(&xt[e][p4 * 4]) = v;
        }
    }
    __syncthreads();

    const int* lp = tgt + (size_t)n * PPIX + pix0;
    float acc = 0.f;
#pragma unroll
    for (int k = 0; k < 2; ++k) {
        const int p = k * 256 + tid;
        const int c = lp[p];
        float d2 = 0.f;
#pragma unroll
        for (int e = 0; e < EDIM; ++e) {
            float d = xt[e][p] - lm[c][e];
            d2 += d * d;
        }
        float h = fmaxf(sqrtf(d2) - 0.5f, 0.f);
        acc += h * h * licnt[c];
    }
    for (int o = 32; o; o >>= 1) acc += __shfl_down(acc, o, 64);
    __shared__ float rs[4];
    if ((tid & 63) == 0) rs[w] = acc;
    __syncthreads();
    if (tid == 0) atomicAdd(&varv[n], rs[0] + rs[1] + rs[2] + rs[3]);
}

__global__ void k_final(const float* __restrict__ varv,
                        const float* __restrict__ tripv,
                        const float* __restrict__ regv,
                        float* __restrict__ out) {
    float s = 0.f;
#pragma unroll
    for (int n = 0; n < NB; ++n)
        s += varv[n] / (float)C_LAB + tripv[n] + regv[n] / (float)C_LAB;
    out[0] = s / (float)(NB * NB);
}

extern "C" void kernel_launch(void* const* d_in, const int* in_sizes, int n_in,
                              void* d_out, int out_size, void* d_ws, size_t ws_size,
                              hipStream_t stream) {
    const float* input = (const float*)d_in[0];
    const int* target = (const int*)d_in[1];
    const int* eattr = (const int*)d_in[2];
    const int* erep = (const int*)d_in[3];
    float* out = (float*)d_out;

    int* counts = (int*)d_ws;
    float* wsf = (float*)d_ws;
    float* sums = wsf + 96;
    float* means = wsf + 1632;
    float* regv = wsf + 3168;
    float* tripv = wsf + 3172;
    float* varv = wsf + 3176;
    float* probev = wsf + 3180;

    k_zero<<<1, 256, 0, stream>>>((int*)d_ws);
    k_probe<<<2048, 256, 0, stream>>>(input, probev);

    k_accum_e<<<dim3(PPIX / 4096, NB, EDIM), 256, 0, stream>>>(input, target, sums, counts);
    k_means<<<1, 128, 0, stream>>>(sums, counts, means, regv);
    k_triplet<<<NB, 256, 0, stream>>>(means, eattr, erep, tripv);
    k_var_t<<<dim3(PPIX / VT_PX, NB), 256, 0, stream>>>(input, target, means, counts, varv);
    k_final<<<1, 1, 0, stream>>>(varv, tripv, regv, out);
}